// Round 1
// baseline (534.208 us; speedup 1.0000x reference)
//
#include <hip/hip_runtime.h>
#include <cstdint>
#include <cstddef>

#define NSAMP 4096
#define KDIM  512
#define TOT   49536   // 3 * (128*128 + 128)
#define NUMN  387     // TOT / 128
#define BK    64
#define LCHUNK 16512  // 128 + 128*128, per-layer temp stride

typedef __attribute__((ext_vector_type(8))) __bf16 bf16x8;
typedef __attribute__((ext_vector_type(4))) __bf16 bf16x4;
typedef __attribute__((ext_vector_type(4))) float  f32x4;

#define AS1 __attribute__((address_space(1)))
#define AS3 __attribute__((address_space(3)))

// ---------------------------------------------------------------------------
// fp32 -> bf16 cast, 4 elements per thread (float4 read, 8B write)
// ---------------------------------------------------------------------------
__global__ void cast_bf16(const float* __restrict__ in, __bf16* __restrict__ out, int n4) {
    int i = blockIdx.x * blockDim.x + threadIdx.x;
    int stride = gridDim.x * blockDim.x;
    for (; i < n4; i += stride) {
        float4 v = ((const float4*)in)[i];
        bf16x4 o = { (__bf16)v.x, (__bf16)v.y, (__bf16)v.z, (__bf16)v.w };
        ((bf16x4*)out)[i] = o;
    }
}

// ---------------------------------------------------------------------------
// Hypernetwork GEMM: C[m][n] = sum_k A[m][k]*B[n][k] + bias[n]
// UNCHANGED from the verified R5 kernel (541.6 us session):
//  (a) XCD-congruent block swizzle (same-B blocks land on same XCD L2)
//  (b) k-invariant staging pointers hoisted out of K-loop
//  16B global_load_lds staging, xor LDS swizzle, 2-barrier K-loop.
// ---------------------------------------------------------------------------
__global__ __launch_bounds__(256) void hyper_gemm(
    const __bf16* __restrict__ A, const __bf16* __restrict__ B,
    const float* __restrict__ bias, __bf16* __restrict__ C)
{
    __shared__ __bf16 As[128 * BK];   // 16 KB
    __shared__ __bf16 Bs[128 * BK];   // 16 KB

    const int tid   = threadIdx.x;
    const int lane  = tid & 63;
    const int quad  = lane >> 4;      // 0..3
    const int r16   = lane & 15;      // 0..15
    const int wv    = tid >> 6;       // 0..3
    const int waveM = wv >> 1;        // 0..1
    const int waveN = wv & 1;         // 0..1

    // ---- XCD-congruent swizzle: hw id -> (m_t, n_t)
    const int num_m = gridDim.y;                    // chunk/128
    const int id    = blockIdx.y * NUMN + blockIdx.x;
    const int gsz   = 8 * num_m;                    // supergroup block count
    const int s     = id / gsz;
    const int r     = id % gsz;
    const int base  = s * 8;
    int w = NUMN - base; if (w > 8) w = 8;          // partial last group (387%8=3)
    const int n_t = base + r % w;
    const int m_t = r / w;

    const int m0 = m_t * 128;   // chunk-local row
    const int n0 = n_t * 128;

    f32x4 acc[4][4] = {};

    // ---- per-thread staging geometry (k-invariant, hoisted)
    const __bf16* gAp[4];
    const __bf16* gBp[4];
    int ldsOff[4];
#pragma unroll
    for (int c = 0; c < 4; ++c) {
        int idx  = c * 256 + tid;           // 0..1023; dest = idx*16B
        int row  = idx >> 3;                // 0..127
        int gsrc = (idx & 7) ^ (row & 7);   // xor-swizzled 16B-group in row
        gAp[c] = A + (size_t)(m0 + row) * KDIM + gsrc * 8;
        gBp[c] = B + (size_t)(n0 + row) * KDIM + gsrc * 8;
        ldsOff[c] = idx * 8;
    }

    const int rsw = r16 & 7;          // read-phase swizzle key

    for (int kt = 0; kt < KDIM / BK; ++kt) {
        const int k0 = kt * BK;
#pragma unroll
        for (int c = 0; c < 4; ++c) {
            __builtin_amdgcn_global_load_lds((AS1 void*)(gAp[c] + k0),
                (AS3 void*)(As + ldsOff[c]), 16, 0, 0);
            __builtin_amdgcn_global_load_lds((AS1 void*)(gBp[c] + k0),
                (AS3 void*)(Bs + ldsOff[c]), 16, 0, 0);
        }
        __syncthreads();

        // --- two sub-k MFMA passes (kk = 0,1), 16 MFMA each
#pragma unroll
        for (int kk = 0; kk < 2; ++kk) {
            bf16x8 af[4], bf[4];
#pragma unroll
            for (int i = 0; i < 4; ++i) {
                int rr = waveM * 64 + i * 16 + r16;
                af[i] = *(const bf16x8*)(As + rr * BK + (((kk * 4 + quad) ^ rsw) * 8));
            }
#pragma unroll
            for (int j = 0; j < 4; ++j) {
                int rr = waveN * 64 + j * 16 + r16;
                bf[j] = *(const bf16x8*)(Bs + rr * BK + (((kk * 4 + quad) ^ rsw) * 8));
            }
#pragma unroll
            for (int i = 0; i < 4; ++i)
#pragma unroll
                for (int j = 0; j < 4; ++j)
                    acc[i][j] = __builtin_amdgcn_mfma_f32_16x16x32_bf16(af[i], bf[j], acc[i][j], 0, 0, 0);
        }
        __syncthreads();
    }

    // --- epilogue: C/D layout col=lane&15, row=(lane>>4)*4+reg. Fuse bias,
    // cast bf16, plain stores (write path measured clean: ~100MB/101.5MB).
#pragma unroll
    for (int j = 0; j < 4; ++j) {
        int n = n0 + waveN * 64 + j * 16 + r16;
        float bb = bias[n];
#pragma unroll
        for (int i = 0; i < 4; ++i) {
            int mbase = m0 + waveM * 64 + i * 16 + quad * 4;
#pragma unroll
            for (int rr = 0; rr < 4; ++rr) {
                C[(size_t)(mbase + rr) * TOT + n] = (__bf16)(acc[i][j][rr] + bb);
            }
        }
    }
}

// ---------------------------------------------------------------------------
// Stage 2: per-sample 3-layer MLP with hypernetwork weights from temp chunk.
// R6 change (T14 async-split): cross-layer weight prefetch. Layer l+1's
// weight addresses are data-independent, so its 8x16B register loads are
// issued BEFORE layer l's compute+reduce+barriers (~1-2k cyc) -> L2/L3
// latency (200-900 cyc) fully hidden for layers 1,2. Bias load hoisted out
// of the tail `if` for the same reason. Layer loop fully unrolled so all
// w[]/wn[] indexing is static (rule #20: no scratch spill).
// ---------------------------------------------------------------------------
__global__ __launch_bounds__(256) void mlp_kernel(
    const float* __restrict__ x, const __bf16* __restrict__ temp,
    float* __restrict__ out, int samp0)
{
    const int n   = samp0 + blockIdx.x;   // global sample index
    const int tid = threadIdx.x;
    const int wv  = tid >> 6;             // 0..3
    const int l   = tid & 63;
    const int pg  = l >> 4;               // 0..3
    const int qg  = l & 15;               // 0..15

    __shared__ float h[128];
    __shared__ float partial[4][128];

    if (tid < 64) ((float2*)h)[tid] = ((const float2*)(x + (size_t)n * 128))[tid];

    const __bf16* row = temp + (size_t)blockIdx.x * TOT;   // chunk-local temp row

    // prefetch layer-0 weights (independent of h)
    bf16x8 w[8];
#pragma unroll
    for (int i = 0; i < 8; ++i)
        w[i] = *(const bf16x8*)(row + 128 + (size_t)(wv * 32 + i * 4 + pg) * 128 + qg * 8);

    int cum = 0;
#pragma unroll
    for (int layer = 0; layer < 3; ++layer) {
        // issue next-layer weight loads early: they retire under this
        // layer's compute + reductions + barriers
        bf16x8 wn[8];
        if (layer < 2) {
#pragma unroll
            for (int i = 0; i < 8; ++i)
                wn[i] = *(const bf16x8*)(row + cum + LCHUNK + 128
                        + (size_t)(wv * 32 + i * 4 + pg) * 128 + qg * 8);
        }
        // bias prefetch (was inside the tail `if`: cold scalar load)
        float bv = 0.f;
        if (tid < 128) bv = (float)row[cum + tid];

        float acc[8] = {0, 0, 0, 0, 0, 0, 0, 0};
        __syncthreads();   // h ready
#pragma unroll
        for (int i = 0; i < 8; ++i) {
            float hp = h[wv * 32 + i * 4 + pg];
#pragma unroll
            for (int j = 0; j < 8; ++j) acc[j] += (float)w[i][j] * hp;
        }
#pragma unroll
        for (int j = 0; j < 8; ++j) {
            acc[j] += __shfl_xor(acc[j], 16);
            acc[j] += __shfl_xor(acc[j], 32);
        }
        if (pg == 0) {
#pragma unroll
            for (int j = 0; j < 8; ++j) partial[wv][qg * 8 + j] = acc[j];
        }
        __syncthreads();   // partials ready; everyone done reading h
        if (tid < 128) {
            float v = partial[0][tid] + partial[1][tid] + partial[2][tid] + partial[3][tid]
                    + bv;
            if (layer < 2) v = fmaxf(v, 0.f);
            h[tid] = v;
        }
        if (layer < 2) {
#pragma unroll
            for (int i = 0; i < 8; ++i) w[i] = wn[i];
        }
        cum += LCHUNK;
    }
    __syncthreads();
    if (tid < 64) ((float2*)(out + (size_t)n * 128))[tid] = ((const float2*)h)[tid];
}

// ---------------------------------------------------------------------------
extern "C" void kernel_launch(void* const* d_in, const int* in_sizes, int n_in,
                              void* d_out, int out_size, void* d_ws, size_t ws_size,
                              hipStream_t stream) {
    const float* int_x = (const float*)d_in[0];  // 4096 x 512
    const float* x     = (const float*)d_in[1];  // 4096 x 128
    const float* W     = (const float*)d_in[2];  // 49536 x 512
    const float* b     = (const float*)d_in[3];  // 49536
    float* out = (float*)d_out;                  // 4096 x 128

    // workspace layout (bf16): A_bf (4 MB) | W_bf (50.7 MB) | temp chunk
    char* ws = (char*)d_ws;
    __bf16* A_bf = (__bf16*)ws;
    size_t offA = (size_t)NSAMP * KDIM * 2;
    __bf16* W_bf = (__bf16*)(ws + offA);
    size_t offW = offA + (size_t)TOT * KDIM * 2;
    __bf16* temp = (__bf16*)(ws + offW);

    // Adaptive chunk: largest of {4096..128} whose temp fits remaining ws.
    // Deterministic given ws_size -> identical work every call (capture-safe).
    size_t remain = (ws_size > offW) ? (ws_size - offW) : 0;
    int chunk = 128;
    for (int c = 4096; c >= 128; c >>= 1) {
        if ((size_t)c * TOT * 2 <= remain) { chunk = c; break; }
    }

    int nA4 = NSAMP * KDIM / 4;
    cast_bf16<<<(nA4 + 255) / 256, 256, 0, stream>>>(int_x, A_bf, nA4);
    int nW4 = TOT * KDIM / 4;
    cast_bf16<<<(nW4 + 255) / 256, 256, 0, stream>>>(W, W_bf, nW4);

    for (int samp0 = 0; samp0 < NSAMP; samp0 += chunk) {
        dim3 grid(NUMN, chunk / 128);   // 387 x (chunk/128)
        hyper_gemm<<<grid, 256, 0, stream>>>(A_bf + (size_t)samp0 * KDIM, W_bf, b, temp);
        mlp_kernel<<<chunk, 256, 0, stream>>>(x, temp, out, samp0);
    }
}

// Round 2
// 531.620 us; speedup vs baseline: 1.0049x; 1.0049x over previous
//
#include <hip/hip_runtime.h>
#include <cstdint>
#include <cstddef>

#define NSAMP 4096
#define KDIM  512
#define TOT   49536   // 3 * (128*128 + 128)
#define TOT_P 49664   // padded to 256-multiple: 194 n-tiles
#define NUMN_P 194
#define LCHUNK 16512  // 128 + 128*128, per-layer temp stride

typedef __attribute__((ext_vector_type(8))) __bf16 bf16x8;
typedef __attribute__((ext_vector_type(4))) __bf16 bf16x4;
typedef __attribute__((ext_vector_type(4))) float  f32x4;

#define AS1 __attribute__((address_space(1)))
#define AS3 __attribute__((address_space(3)))

// ---------------------------------------------------------------------------
// fp32 -> bf16 cast, 4 elements per thread (float4 read, 8B write)
// ---------------------------------------------------------------------------
__global__ void cast_bf16(const float* __restrict__ in, __bf16* __restrict__ out, int n4) {
    int i = blockIdx.x * blockDim.x + threadIdx.x;
    int stride = gridDim.x * blockDim.x;
    for (; i < n4; i += stride) {
        float4 v = ((const float4*)in)[i];
        bf16x4 o = { (__bf16)v.x, (__bf16)v.y, (__bf16)v.z, (__bf16)v.w };
        ((bf16x4*)out)[i] = o;
    }
}

// ---------------------------------------------------------------------------
// Hypernetwork GEMM, 256x256 tile, 8-wave (2M x 4N), BK=64, 8-phase schedule
// with counted vmcnt (T3+T4), setprio around MFMA clusters (T5), xor-granule
// LDS swizzle (proven 0 bank conflicts in the 128^2 predecessor), XCD-
// congruent block swizzle (T1). K=512 -> 8 K-tiles: prologue + 3 steady
// iterations (2 K-tiles each) + peeled tail iteration.
//
// Race-freedom by construction:
//  - each LDS region (Ae/Be/Ao/Bo x half) is staged only in a phase strictly
//    after the last phase that ds_reads its old contents (readers complete
//    before their phase's MFMA via lgkmcnt(0); stage is issued after that
//    phase's end barrier).
//  - steady-state waits: vmcnt(4) at ph4/ph8 = 12 loads outstanding, retire
//    oldest 8 = exactly the 4 half-tiles read next; tail uses vmcnt(0).
//  - raw asm s_barrier (memory clobber) so no implicit vmcnt(0) drain.
// ---------------------------------------------------------------------------
__global__ __launch_bounds__(512, 2) void hyper_gemm(
    const __bf16* __restrict__ A, const __bf16* __restrict__ B,
    const float* __restrict__ bias, __bf16* __restrict__ C)
{
    __shared__ __bf16 lds[65536];        // 128 KB: Ae | Be | Ao | Bo
    __bf16* Ae = lds;
    __bf16* Be = lds + 16384;
    __bf16* Ao = lds + 32768;
    __bf16* Bo = lds + 49152;

    const int tid  = threadIdx.x;
    const int lane = tid & 63;
    const int quad = lane >> 4;       // 0..3
    const int r16  = lane & 15;       // 0..15
    const int wv   = tid >> 6;        // 0..7
    const int waveN = wv & 3;         // 0..3
    const int waveM = wv >> 2;        // 0..1

    // ---- XCD-congruent swizzle: same-n_t blocks -> same XCD, adjacent ids
    const int num_m = gridDim.y;
    const int id  = blockIdx.y * gridDim.x + blockIdx.x;
    const int gsz = 8 * num_m;
    const int sg  = id / gsz;
    const int r   = id % gsz;
    const int base = sg * 8;
    int w = gridDim.x - base; if (w > 8) w = 8;   // 194 % 8 = 2 tail group
    const int n_t = base + r % w;
    const int m_t = r / w;
    const int m0 = m_t * 256;    // chunk-local row
    const int n0 = n_t * 256;

    // ---- staging geometry: two 16B loads per thread per half-tile
    // idx = c*512+tid; row = idx>>3 (0..127 within half), granule = idx&7;
    // global granule pre-swizzled by row&7 so LDS stays linear (dest =
    // uniform + lane*16B as global_load_lds requires).
    const int row0 = tid >> 3;
    const int g0   = tid & 7;
    const int aO0 = (m0 + row0) * KDIM + ((g0 ^ (row0 & 7)) * 8);
    const int aO1 = aO0 + 64 * KDIM;            // row1 = row0 + 64, same g/swz
    const int bO0 = (n0 + row0) * KDIM + ((g0 ^ (row0 & 7)) * 8);
    const int bO1 = bO0 + 64 * KDIM;
    const int ldsO0 = tid * 8;
    const int ldsO1 = 4096 + tid * 8;

#define STAGE_A(REG, half, tile) do { \
    __builtin_amdgcn_global_load_lds((AS1 void*)(A + aO0 + (half)*65536 + (tile)*64), \
        (AS3 void*)((REG) + (half)*8192 + ldsO0), 16, 0, 0); \
    __builtin_amdgcn_global_load_lds((AS1 void*)(A + aO1 + (half)*65536 + (tile)*64), \
        (AS3 void*)((REG) + (half)*8192 + ldsO1), 16, 0, 0); \
} while (0)
#define STAGE_B(REG, half, tile) do { \
    __builtin_amdgcn_global_load_lds((AS1 void*)(B + bO0 + (half)*65536 + (tile)*64), \
        (AS3 void*)((REG) + (half)*8192 + ldsO0), 16, 0, 0); \
    __builtin_amdgcn_global_load_lds((AS1 void*)(B + bO1 + (half)*65536 + (tile)*64), \
        (AS3 void*)((REG) + (half)*8192 + ldsO1), 16, 0, 0); \
} while (0)

    // ---- read-side offsets (elements); row&7 == r16&7 for all fragments
    const int rsw = r16 & 7;
    const int aRd = (waveM * 128 + r16) * 64;
    const int bRd = (waveN * 64 + r16) * 64;
    const int kg0 = ((0 * 4 + quad) ^ rsw) * 8;
    const int kg1 = ((1 * 4 + quad) ^ rsw) * 8;

    f32x4 acc[8][4] = {};
    bf16x8 af[4][2], bf0[2][2], bf1[2][2];

#define LDA_(BUF, mq) { _Pragma("unroll") for (int i4 = 0; i4 < 4; ++i4) { \
    af[i4][0] = *(const bf16x8*)((BUF) + aRd + (mq)*4096 + i4*1024 + kg0); \
    af[i4][1] = *(const bf16x8*)((BUF) + aRd + (mq)*4096 + i4*1024 + kg1); } }
#define LDB0_(BUF) { _Pragma("unroll") for (int j2 = 0; j2 < 2; ++j2) { \
    bf0[j2][0] = *(const bf16x8*)((BUF) + bRd + j2*1024 + kg0); \
    bf0[j2][1] = *(const bf16x8*)((BUF) + bRd + j2*1024 + kg1); } }
#define LDB1_(BUF) { _Pragma("unroll") for (int j2 = 0; j2 < 2; ++j2) { \
    bf1[j2][0] = *(const bf16x8*)((BUF) + bRd + 2048 + j2*1024 + kg0); \
    bf1[j2][1] = *(const bf16x8*)((BUF) + bRd + 2048 + j2*1024 + kg1); } }
#define MFMA16_(MQ, NQ, BF) { _Pragma("unroll") for (int i4 = 0; i4 < 4; ++i4) \
    _Pragma("unroll") for (int j2 = 0; j2 < 2; ++j2) { \
      acc[(MQ)*4+i4][(NQ)*2+j2] = __builtin_amdgcn_mfma_f32_16x16x32_bf16( \
          af[i4][0], BF[j2][0], acc[(MQ)*4+i4][(NQ)*2+j2], 0, 0, 0); \
      acc[(MQ)*4+i4][(NQ)*2+j2] = __builtin_amdgcn_mfma_f32_16x16x32_bf16( \
          af[i4][1], BF[j2][1], acc[(MQ)*4+i4][(NQ)*2+j2], 0, 0, 0); } }

#define BARRIER_ asm volatile("s_barrier" ::: "memory")
#define LGKM8_   asm volatile("s_waitcnt lgkmcnt(8)" ::: "memory")
#define LGKM0_   asm volatile("s_waitcnt lgkmcnt(0)" ::: "memory"); __builtin_amdgcn_sched_barrier(0)
#define PRIO1_   __builtin_amdgcn_s_setprio(1)
#define PRIO0_   __builtin_amdgcn_s_setprio(0); __builtin_amdgcn_sched_barrier(0)
#define VM4_     asm volatile("s_waitcnt vmcnt(4)" ::: "memory")
#define VM0_     asm volatile("s_waitcnt vmcnt(0)" ::: "memory")

    // ---- prologue: tile0 (B,A) + tile1 (B); retire tile0, keep B(1) flying
    STAGE_B(Be, 0, 0); STAGE_B(Be, 1, 0);
    STAGE_A(Ae, 0, 0); STAGE_A(Ae, 1, 0);
    STAGE_B(Bo, 0, 1); STAGE_B(Bo, 1, 1);
    VM4_; BARRIER_;

    // ---- steady iterations: tiles (2i, 2i+1); stage A(2i+1), B/A(2i+2), B(2i+3)
    for (int it = 0; it < 3; ++it) {
        const int t = 2 * it;
        // ph1: even tile, quad M0N0
        LDA_(Ae, 0); LDB0_(Be); STAGE_A(Ao, 0, t + 1); LGKM8_;
        BARRIER_; LGKM0_; PRIO1_; MFMA16_(0, 0, bf0); PRIO0_; BARRIER_;
        // ph2: M0N1
        LDB1_(Be); STAGE_A(Ao, 1, t + 1);
        BARRIER_; LGKM0_; PRIO1_; MFMA16_(0, 1, bf1); PRIO0_; BARRIER_;
        // ph3: M1N0
        LDA_(Ae, 1); STAGE_B(Be, 0, t + 2);
        BARRIER_; LGKM0_; PRIO1_; MFMA16_(1, 0, bf0); PRIO0_; BARRIER_;
        // ph4: M1N1  (+ counted wait: tile 2i+1 must be landed for ph5)
        STAGE_B(Be, 1, t + 2);
        BARRIER_; LGKM0_; PRIO1_; MFMA16_(1, 1, bf1); PRIO0_; VM4_; BARRIER_;
        // ph5: odd tile, M0N0
        LDA_(Ao, 0); LDB0_(Bo); STAGE_A(Ae, 0, t + 2); LGKM8_;
        BARRIER_; LGKM0_; PRIO1_; MFMA16_(0, 0, bf0); PRIO0_; BARRIER_;
        // ph6: M0N1
        LDB1_(Bo); STAGE_A(Ae, 1, t + 2);
        BARRIER_; LGKM0_; PRIO1_; MFMA16_(0, 1, bf1); PRIO0_; BARRIER_;
        // ph7: M1N0
        LDA_(Ao, 1); STAGE_B(Bo, 0, t + 3);
        BARRIER_; LGKM0_; PRIO1_; MFMA16_(1, 0, bf0); PRIO0_; BARRIER_;
        // ph8: M1N1 (+ counted wait: tile 2i+2 must be landed for next ph1)
        STAGE_B(Bo, 1, t + 3);
        BARRIER_; LGKM0_; PRIO1_; MFMA16_(1, 1, bf1); PRIO0_; VM4_; BARRIER_;
    }

    // ---- peeled tail: tiles 6,7 (stage only A(7); drain with vmcnt(0))
    LDA_(Ae, 0); LDB0_(Be); STAGE_A(Ao, 0, 7); LGKM8_;
    BARRIER_; LGKM0_; PRIO1_; MFMA16_(0, 0, bf0); PRIO0_; BARRIER_;
    LDB1_(Be); STAGE_A(Ao, 1, 7);
    BARRIER_; LGKM0_; PRIO1_; MFMA16_(0, 1, bf1); PRIO0_; BARRIER_;
    LDA_(Ae, 1);
    BARRIER_; LGKM0_; PRIO1_; MFMA16_(1, 0, bf0); PRIO0_; BARRIER_;
    BARRIER_; LGKM0_; PRIO1_; MFMA16_(1, 1, bf1); PRIO0_; VM0_; BARRIER_;
    LDA_(Ao, 0); LDB0_(Bo);
    BARRIER_; LGKM0_; PRIO1_; MFMA16_(0, 0, bf0); PRIO0_; BARRIER_;
    LDB1_(Bo);
    BARRIER_; LGKM0_; PRIO1_; MFMA16_(0, 1, bf1); PRIO0_; BARRIER_;
    LDA_(Ao, 1);
    BARRIER_; LGKM0_; PRIO1_; MFMA16_(1, 0, bf0); PRIO0_; BARRIER_;
    BARRIER_; LGKM0_; PRIO1_; MFMA16_(1, 1, bf1); PRIO0_;

    // ---- epilogue: C/D layout col=lane&15, row=(lane>>4)*4+reg; fuse bias,
    // cast bf16. Pad columns (n >= TOT) get garbage with zero bias; the MLP
    // stage never reads them.
#pragma unroll
    for (int j = 0; j < 4; ++j) {
        int n = n0 + waveN * 64 + j * 16 + r16;
        float bb = (n < TOT) ? bias[n] : 0.f;
#pragma unroll
        for (int i = 0; i < 8; ++i) {
            int mrow = m0 + waveM * 128 + i * 16 + quad * 4;
#pragma unroll
            for (int rr = 0; rr < 4; ++rr) {
                C[(size_t)(mrow + rr) * TOT_P + n] = (__bf16)(acc[i][j][rr] + bb);
            }
        }
    }
#undef STAGE_A
#undef STAGE_B
#undef LDA_
#undef LDB0_
#undef LDB1_
#undef MFMA16_
#undef BARRIER_
#undef LGKM8_
#undef LGKM0_
#undef PRIO1_
#undef PRIO0_
#undef VM4_
#undef VM0_
}

// ---------------------------------------------------------------------------
// Stage 2: per-sample 3-layer MLP with hypernetwork weights from temp chunk.
// (Unchanged from R6 except temp row stride = TOT_P.) Cross-layer weight
// prefetch (T14): layer l+1's 8x16B loads issued before layer l's
// compute+reduce+barriers; bias hoisted.
// ---------------------------------------------------------------------------
__global__ __launch_bounds__(256) void mlp_kernel(
    const float* __restrict__ x, const __bf16* __restrict__ temp,
    float* __restrict__ out, int samp0)
{
    const int n   = samp0 + blockIdx.x;   // global sample index
    const int tid = threadIdx.x;
    const int wv  = tid >> 6;             // 0..3
    const int l   = tid & 63;
    const int pg  = l >> 4;               // 0..3
    const int qg  = l & 15;               // 0..15

    __shared__ float h[128];
    __shared__ float partial[4][128];

    if (tid < 64) ((float2*)h)[tid] = ((const float2*)(x + (size_t)n * 128))[tid];

    const __bf16* row = temp + (size_t)blockIdx.x * TOT_P;  // padded row stride

    // prefetch layer-0 weights (independent of h)
    bf16x8 w[8];
#pragma unroll
    for (int i = 0; i < 8; ++i)
        w[i] = *(const bf16x8*)(row + 128 + (size_t)(wv * 32 + i * 4 + pg) * 128 + qg * 8);

    int cum = 0;
#pragma unroll
    for (int layer = 0; layer < 3; ++layer) {
        bf16x8 wn[8];
        if (layer < 2) {
#pragma unroll
            for (int i = 0; i < 8; ++i)
                wn[i] = *(const bf16x8*)(row + cum + LCHUNK + 128
                        + (size_t)(wv * 32 + i * 4 + pg) * 128 + qg * 8);
        }
        float bv = 0.f;
        if (tid < 128) bv = (float)row[cum + tid];

        float acc[8] = {0, 0, 0, 0, 0, 0, 0, 0};
        __syncthreads();   // h ready
#pragma unroll
        for (int i = 0; i < 8; ++i) {
            float hp = h[wv * 32 + i * 4 + pg];
#pragma unroll
            for (int j = 0; j < 8; ++j) acc[j] += (float)w[i][j] * hp;
        }
#pragma unroll
        for (int j = 0; j < 8; ++j) {
            acc[j] += __shfl_xor(acc[j], 16);
            acc[j] += __shfl_xor(acc[j], 32);
        }
        if (pg == 0) {
#pragma unroll
            for (int j = 0; j < 8; ++j) partial[wv][qg * 8 + j] = acc[j];
        }
        __syncthreads();   // partials ready; everyone done reading h
        if (tid < 128) {
            float v = partial[0][tid] + partial[1][tid] + partial[2][tid] + partial[3][tid]
                    + bv;
            if (layer < 2) v = fmaxf(v, 0.f);
            h[tid] = v;
        }
        if (layer < 2) {
#pragma unroll
            for (int i = 0; i < 8; ++i) w[i] = wn[i];
        }
        cum += LCHUNK;
    }
    __syncthreads();
    if (tid < 64) ((float2*)(out + (size_t)n * 128))[tid] = ((const float2*)h)[tid];
}

// ---------------------------------------------------------------------------
extern "C" void kernel_launch(void* const* d_in, const int* in_sizes, int n_in,
                              void* d_out, int out_size, void* d_ws, size_t ws_size,
                              hipStream_t stream) {
    const float* int_x = (const float*)d_in[0];  // 4096 x 512
    const float* x     = (const float*)d_in[1];  // 4096 x 128
    const float* W     = (const float*)d_in[2];  // 49536 x 512
    const float* b     = (const float*)d_in[3];  // 49536
    float* out = (float*)d_out;                  // 4096 x 128

    // workspace layout (bf16): A_bf (4 MB) | W_bf (padded rows, 50.9 MB) | temp
    char* ws = (char*)d_ws;
    __bf16* A_bf = (__bf16*)ws;
    size_t offA = (size_t)NSAMP * KDIM * 2;
    __bf16* W_bf = (__bf16*)(ws + offA);
    size_t offW = offA + (size_t)TOT_P * KDIM * 2;   // pad rows: garbage, only
    __bf16* temp = (__bf16*)(ws + offW);             // feeds pad temp columns

    // Adaptive chunk: largest of {4096..256} whose padded temp fits remaining
    // ws. Deterministic given ws_size (capture-safe). chunk % 256 == 0.
    size_t remain = (ws_size > offW) ? (ws_size - offW) : 0;
    int chunk = 256;
    for (int c = 4096; c >= 256; c >>= 1) {
        if ((size_t)c * TOT_P * 2 <= remain) { chunk = c; break; }
    }

    int nA4 = NSAMP * KDIM / 4;
    cast_bf16<<<(nA4 + 255) / 256, 256, 0, stream>>>(int_x, A_bf, nA4);
    int nW4 = TOT * KDIM / 4;
    cast_bf16<<<(nW4 + 255) / 256, 256, 0, stream>>>(W, W_bf, nW4);

    for (int samp0 = 0; samp0 < NSAMP; samp0 += chunk) {
        dim3 grid(NUMN_P, chunk / 256);   // 194 x (chunk/256)
        hyper_gemm<<<grid, 512, 0, stream>>>(A_bf + (size_t)samp0 * KDIM, W_bf, b, temp);
        mlp_kernel<<<chunk, 256, 0, stream>>>(x, temp, out, samp0);
    }
}